// Round 2
// baseline (236.387 us; speedup 1.0000x reference)
//
#include <hip/hip_runtime.h>

// Collapsed problem (channel-sum commutes with the linear conv):
//   out[n,d,h,w] = sum_{i,kd,kh,kw} x[n,i,d+kd,h+kh,w+kw] * Wsum[i,kd,kh,kw] + C
//   Wsum = 0.5 * sum_o conv_weight[o,...]   (32*27 = 864 floats)
//   C    = sum_o (0.5*conv_bias[o] + bias[o])
// x: (8,32,32,64,64) fp32; out: (8,30,62,62) fp32.

#define XD 32
#define XH 64
#define XW 64
#define DOUT 30
#define HOUT 62
#define WOUT 62
#define DT 4           // output d per block
#define HT 8           // output h per block
#define TILE_SLICES 6  // DT+2
#define TILE_ROWS 10   // HT+2
#define TILE_FLOATS (TILE_SLICES * TILE_ROWS * 64)  // 3840 floats = 15 KiB
#define CHUNKS (TILE_FLOATS / 4)                    // 960 x 16B chunks
#define CH_STRIDE (XD * XH * XW)                    // floats per channel

__global__ __launch_bounds__(256, 2)
void conv3d_chansum_kernel(const float* __restrict__ x,
                           const float* __restrict__ cw,
                           const float* __restrict__ cb,
                           const float* __restrict__ pb,
                           float* __restrict__ out) {
  __shared__ float tile[2][TILE_FLOATS];  // double buffer, 30 KiB
  __shared__ float wl[897];               // [32][28] padded Wsum + wl[896]=C

  const int tid = threadIdx.x;
  const int hb = blockIdx.x;  // 0..7
  const int db = blockIdx.y;  // 0..7
  const int n  = blockIdx.z;  // 0..7
  const int h0 = hb * HT;
  const int d0 = db * DT;

  // thread -> (dt, ht, w-strip s). A wave = 8 consecutive rows x 8 strips.
  const int s    = tid & 7;
  const int slot = tid >> 3;
  const int dt   = slot >> 3;
  const int ht   = slot & 7;

  const float* xn = x + (size_t)n * (32u * CH_STRIDE);

  // ---- hoisted staging addresses (channel-invariant) ----
  // LDS chunk k (16B): slice sd=k/160, row r=(k%160)>>4, chunk c=k&15.
  // LDS[sd][r][c] holds global chunk (c ^ key), key=(sd*10+r)&15  (XOR involution).
  int  soff[4];
  bool svalid[4];
#pragma unroll
  for (int round = 0; round < 4; ++round) {
    int k   = tid + round * 256;
    int sd  = k / 160;
    int rem = k - sd * 160;
    int r   = rem >> 4;
    int c   = rem & 15;
    int csrc = c ^ ((sd * 10 + r) & 15);
    int dd = d0 + sd, hh = h0 + r;
    svalid[round] = (k < CHUNKS) & (dd < XD) & (hh < XH);
    soff[round]   = dd * (XH * XW) + hh * XW + csrc * 4;
  }
  const int ldsoff = (tid & ~63) * 4;  // wave-uniform float offset (+ round*1024)

  auto stage = [&](float* buf, int ch) {
    const float* xnc = xn + (size_t)ch * CH_STRIDE;
#pragma unroll
    for (int round = 0; round < 4; ++round) {
      if (svalid[round]) {
        __builtin_amdgcn_global_load_lds(
            (const __attribute__((address_space(1))) void*)(xnc + soff[round]),
            (__attribute__((address_space(3))) void*)(buf + round * 1024 + ldsoff),
            16, 0, 0);
      }
    }
  };

  float acc[8];
#pragma unroll
  for (int j = 0; j < 8; ++j) acc[j] = 0.f;

  // prologue: issue channel-0 staging; weight pre-sum overlaps the load latency
  stage(tile[0], 0);
  for (int e = tid; e < 864; e += 256) {
    int i = e / 27;
    int j = e - i * 27;
    float ssum = 0.f;
#pragma unroll 8
    for (int o = 0; o < 64; ++o) ssum += cw[o * 864 + e];
    wl[i * 28 + j] = 0.5f * ssum;
  }
  if (tid == 0) {
    float ssum = 0.f;
    for (int o = 0; o < 64; ++o) ssum += 0.5f * cb[o] + pb[o];
    wl[896] = ssum;
  }
  __syncthreads();  // implicit vmcnt(0): tile[0] staged, wl visible

#pragma unroll 1
  for (int ch = 0; ch < 32; ++ch) {
    const float* buf = tile[ch & 1];
    // issue next channel's loads FIRST -> latency hides under this channel's FMAs.
    // WAR safe: tile[cur^1] was last read before the previous barrier.
    if (ch < 31) stage(tile[(ch & 1) ^ 1], ch + 1);

    float wr[28];
#pragma unroll
    for (int q = 0; q < 7; ++q)
      *(float4*)&wr[4 * q] = *(const float4*)&wl[ch * 28 + 4 * q];

#pragma unroll
    for (int kd = 0; kd < 3; ++kd) {
#pragma unroll
      for (int kh = 0; kh < 3; ++kh) {
        const int row  = (dt + kd) * TILE_ROWS + (ht + kh);
        const int key  = row & 15;
        const int base = row * 64;
        // 10 floats x[row][8s .. 8s+9] via swizzled chunks (read-side XOR = store-side XOR)
        float4 a  = *(const float4*)&buf[base + (((2 * s) ^ key) << 2)];
        float4 b  = *(const float4*)&buf[base + (((2 * s + 1) ^ key) << 2)];
        float2 c2 = *(const float2*)&buf[base + ((((2 * s + 2) & 15) ^ key) << 2)];
        float xv[10] = {a.x, a.y, a.z, a.w, b.x, b.y, b.z, b.w, c2.x, c2.y};
        const int wb = kd * 9 + kh * 3;
#pragma unroll
        for (int j = 0; j < 8; ++j)
          acc[j] = fmaf(xv[j], wr[wb],
                   fmaf(xv[j + 1], wr[wb + 1],
                   fmaf(xv[j + 2], wr[wb + 2], acc[j])));
      }
    }

    // single barrier per channel: orders WAR for next stage AND (via the
    // compiler's vmcnt(0) drain before s_barrier) completes ch+1's loads.
    __syncthreads();
  }

  // epilogue: out[n][d0+dt][h0+ht][8s .. 8s+7], masked at the ragged edges
  const float Cc  = wl[896];
  const int   dow = d0 + dt, how = h0 + ht;
  if (dow < DOUT && how < HOUT) {
    float* op = out + (((size_t)n * DOUT + dow) * HOUT + how) * WOUT + s * 8;
    const int nw = min(8, WOUT - s * 8);
#pragma unroll
    for (int j = 0; j < 4; ++j) {
      if (2 * j < nw) {
        float2 v;
        v.x = acc[2 * j] + Cc;
        v.y = acc[2 * j + 1] + Cc;
        *(float2*)&op[2 * j] = v;
      }
    }
  }
}

extern "C" void kernel_launch(void* const* d_in, const int* in_sizes, int n_in,
                              void* d_out, int out_size, void* d_ws, size_t ws_size,
                              hipStream_t stream) {
  const float* x  = (const float*)d_in[0];  // (8,32,32,64,64)
  const float* cw = (const float*)d_in[1];  // (64,32,3,3,3)
  const float* cb = (const float*)d_in[2];  // (64,)
  const float* pb = (const float*)d_in[3];  // (64,1,1,1)
  float* out = (float*)d_out;               // (8,30,62,62)

  dim3 grid(8, 8, 8);  // (hb, db, n) -> 512 blocks = 2 per CU
  conv3d_chansum_kernel<<<grid, 256, 0, stream>>>(x, cw, cb, pb, out);
}